// Round 1
// baseline (164.116 us; speedup 1.0000x reference)
//
#include <hip/hip_runtime.h>

// Problem constants (fixed by the reference's IRREPS = 32x0e+16x1o+8x2e):
//   dim = 120, B = 2048, cb_height = 14400 (derived at launch from out_size/B).
#define DIM 120
#define BLOCK 256

// Build CSR row pointers from the (already sorted, non-decreasing) out_indices.
// row_start[o] = first k with out_indices[k] >= o.  o in [0, H].
__global__ void row_ptr_kernel(const int* __restrict__ out_idx, int K, int H,
                               int* __restrict__ row_start) {
    int o = blockIdx.x * blockDim.x + threadIdx.x;
    if (o > H) return;
    int lo = 0, hi = K;
    while (lo < hi) {
        int mid = (lo + hi) >> 1;
        if (out_idx[mid] < o) lo = mid + 1; else hi = mid;
    }
    row_start[o] = lo;
}

// One thread per output element (b, o).  Block = 256 consecutive o for one b:
// coalesced output stores; in1/in2 rows (120 floats) staged in LDS.
__global__ void tp_kernel(const float* __restrict__ in1,
                          const float* __restrict__ in2,
                          const float* __restrict__ palette,
                          const int* __restrict__ i1,
                          const int* __restrict__ i2,
                          const int* __restrict__ cb,
                          const int* __restrict__ row_start,
                          float* __restrict__ out, int H) {
    __shared__ float s1[DIM];
    __shared__ float s2[DIM];
    const int b = blockIdx.y;
    const float* __restrict__ r1 = in1 + (size_t)b * DIM;
    const float* __restrict__ r2 = in2 + (size_t)b * DIM;
    for (int t = threadIdx.x; t < DIM; t += BLOCK) {
        s1[t] = r1[t];
        s2[t] = r2[t];
    }
    __syncthreads();

    const int o = blockIdx.x * BLOCK + threadIdx.x;
    if (o >= H) return;
    const int k0 = row_start[o];
    const int k1 = row_start[o + 1];
    float acc = 0.0f;
    for (int k = k0; k < k1; ++k) {
        acc += palette[cb[k]] * s1[i1[k]] * s2[i2[k]];
    }
    out[(size_t)b * H + o] = acc;
}

extern "C" void kernel_launch(void* const* d_in, const int* in_sizes, int n_in,
                              void* d_out, int out_size, void* d_ws, size_t ws_size,
                              hipStream_t stream) {
    const float* in1 = (const float*)d_in[0];
    const float* in2 = (const float*)d_in[1];
    const float* pal = (const float*)d_in[2];
    const int*   i1  = (const int*)d_in[3];
    const int*   i2  = (const int*)d_in[4];
    const int*   oi  = (const int*)d_in[5];
    const int*   cb  = (const int*)d_in[6];

    const int K = in_sizes[3];
    const int B = in_sizes[0] / DIM;   // 2048
    const int H = out_size / B;        // 14400

    int* row_start = (int*)d_ws;       // (H+1) ints, recomputed every call

    {
        const int n = H + 1;
        row_ptr_kernel<<<(n + 255) / 256, 256, 0, stream>>>(oi, K, H, row_start);
    }

    dim3 grid((H + BLOCK - 1) / BLOCK, B);
    tp_kernel<<<grid, BLOCK, 0, stream>>>(in1, in2, pal, i1, i2, cb, row_start,
                                          (float*)d_out, H);
}

// Round 2
// 35.275 us; speedup vs baseline: 4.6525x; 4.6525x over previous
//
#include <hip/hip_runtime.h>

#define DIM 120
#define NB 16            // batch rows per block
#define BLOCK 256        // one thread per output row; 256 rows per block

// ---- Preprocess 1: CSR row pointers from sorted out_indices ----
__global__ void row_ptr_kernel(const int* __restrict__ out_idx, int K, int H,
                               int* __restrict__ row_start) {
    int o = blockIdx.x * blockDim.x + threadIdx.x;
    if (o > H) return;
    int lo = 0, hi = K;
    while (lo < hi) {
        int mid = (lo + hi) >> 1;
        if (out_idx[mid] < o) lo = mid + 1; else hi = mid;
    }
    row_start[o] = lo;
}

// ---- Preprocess 2: pack {i1, i2, palette[cb]} into 8 bytes ----
__global__ void pack_kernel(const int* __restrict__ i1, const int* __restrict__ i2,
                            const int* __restrict__ cb, const float* __restrict__ pal,
                            int K, uint2* __restrict__ ent) {
    int k = blockIdx.x * blockDim.x + threadIdx.x;
    if (k >= K) return;
    uint2 e;
    e.x = (unsigned)i1[k] | ((unsigned)i2[k] << 16);
    e.y = __float_as_uint(pal[cb[k]]);
    ent[k] = e;
}

// ---- Main: thread = one output row o x NB batch rows ----
__global__ __launch_bounds__(BLOCK) void tp_kernel(
    const float* __restrict__ in1, const float* __restrict__ in2,
    const uint2* __restrict__ ent, const int* __restrict__ row_start,
    float* __restrict__ out, int H) {
    __shared__ float s1[NB * DIM];
    __shared__ float s2[NB * DIM];

    const int b0 = blockIdx.y * NB;
    // NB rows of in1/in2 are contiguous: stage with float4 (NB*DIM*4 = 7680 B, 16B-aligned)
    {
        const float4* __restrict__ p1 = (const float4*)(in1 + (size_t)b0 * DIM);
        const float4* __restrict__ p2 = (const float4*)(in2 + (size_t)b0 * DIM);
        float4* q1 = (float4*)s1;
        float4* q2 = (float4*)s2;
        for (int t = threadIdx.x; t < NB * DIM / 4; t += BLOCK) {
            q1[t] = p1[t];
            q2[t] = p2[t];
        }
    }
    __syncthreads();

    const int o = blockIdx.x * BLOCK + threadIdx.x;
    if (o >= H) return;
    const int k0 = row_start[o];
    const int k1 = row_start[o + 1];

    float acc[NB];
#pragma unroll
    for (int b = 0; b < NB; ++b) acc[b] = 0.0f;

    for (int k = k0; k < k1; ++k) {
        const uint2 e = ent[k];
        const int a = e.x & 0xffff;
        const int c = e.x >> 16;
        const float v = __uint_as_float(e.y);
#pragma unroll
        for (int b = 0; b < NB; ++b)
            acc[b] += v * s1[b * DIM + a] * s2[b * DIM + c];
    }

#pragma unroll
    for (int b = 0; b < NB; ++b)
        out[(size_t)(b0 + b) * H + o] = acc[b];
}

extern "C" void kernel_launch(void* const* d_in, const int* in_sizes, int n_in,
                              void* d_out, int out_size, void* d_ws, size_t ws_size,
                              hipStream_t stream) {
    const float* in1 = (const float*)d_in[0];
    const float* in2 = (const float*)d_in[1];
    const float* pal = (const float*)d_in[2];
    const int*   i1  = (const int*)d_in[3];
    const int*   i2  = (const int*)d_in[4];
    const int*   oi  = (const int*)d_in[5];
    const int*   cb  = (const int*)d_in[6];

    const int K = in_sizes[3];
    const int B = in_sizes[0] / DIM;   // 2048
    const int H = out_size / B;        // 14400

    // workspace layout: [entries K*8B][row_start (H+1)*4B]
    uint2* ent = (uint2*)d_ws;
    int* row_start = (int*)((char*)d_ws + (size_t)K * sizeof(uint2));

    row_ptr_kernel<<<(H + 1 + 255) / 256, 256, 0, stream>>>(oi, K, H, row_start);
    pack_kernel<<<(K + 255) / 256, 256, 0, stream>>>(i1, i2, cb, pal, K, ent);

    dim3 grid((H + BLOCK - 1) / BLOCK, B / NB);
    tp_kernel<<<grid, BLOCK, 0, stream>>>(in1, in2, ent, row_start,
                                          (float*)d_out, H);
}